// Round 7
// baseline (566.055 us; speedup 1.0000x reference)
//
#include <hip/hip_runtime.h>
#include <math.h>

// SoftclDiceLoss on (B,C,D,H,W) = (2,1,64,256,256) float32.
// R7: 8-floats-per-thread (2x float4) skeletonize iteration.
//   mp[q]  = 7-point cross min of x (LDS, ring 2)  -- 12 b128 reads / 8 outputs
//   hw9[q] = 3x3 HW-max of mp[q]   (registers, ring 3 over D)
//   out[d=q-1] = relu(x - (max(hw9[d-1..d+1]) - mp_center[d]))
// Block: 128 threads = 32 rows x 4 col-jobs of 8 floats; tile 32x32; CD=8.
// LDS 37.3 KB -> 4 blocks/CU; grid 1024 = exact residency. One barrier/plane.

constexpr int B  = 2;
constexpr int D  = 64;
constexpr int H  = 256;
constexpr int W  = 256;
constexpr int HW = H * W;           // 65536
constexpr int NV = B * D * H * W;   // 8388608

constexpr int TW = 32;              // tile (TH=32 implied by 32 rows)
constexpr int CD = 8;               // D-chunk per block
constexpr int XS = 44;              // LDS row stride floats (11 quads, odd)
constexpr int XH = 36;              // x plane rows (halo 2)
constexpr int MH = 34;              // mp plane rows (halo 1)
// x  row xr <-> gh = h0-2+xr ; float f <-> gw = w0-4+f  (f in 0..39)
// mp row mr <-> gh = h0-1+mr ; float f <-> gw = w0-4+f  (same W origin as x;
//   only f = 3..36 are ever consumed by the max stage)

__device__ __forceinline__ float4 vmin4(float4 a, float4 b) {
    return make_float4(fminf(a.x,b.x), fminf(a.y,b.y), fminf(a.z,b.z), fminf(a.w,b.w));
}
__device__ __forceinline__ float4 vmax4(float4 a, float4 b) {
    return make_float4(fmaxf(a.x,b.x), fmaxf(a.y,b.y), fmaxf(a.z,b.z), fmaxf(a.w,b.w));
}
__device__ __forceinline__ float4 sh1(float4 a, float4 b) { return make_float4(a.y,a.z,a.w,b.x); }
__device__ __forceinline__ float4 sh3(float4 a, float4 b) { return make_float4(a.w,b.x,b.y,b.z); }

__global__ __launch_bounds__(256) void prep_kernel(const float* __restrict__ logits,
                                                   const float* __restrict__ target,
                                                   const float* __restrict__ mask,
                                                   float* __restrict__ pred,
                                                   float* __restrict__ tgt) {
    int i = (blockIdx.x * 256 + threadIdx.x) * 4;
    float4 lg = *(const float4*)(logits + i);
    float4 tg = *(const float4*)(target + i);
    float4 mk = *(const float4*)(mask + i);
    float4 p, t;
    p.x = (1.0f/(1.0f+expf(-lg.x)))*mk.x;  t.x = tg.x*mk.x;
    p.y = (1.0f/(1.0f+expf(-lg.y)))*mk.y;  t.y = tg.y*mk.y;
    p.z = (1.0f/(1.0f+expf(-lg.z)))*mk.z;  t.z = tg.z*mk.z;
    p.w = (1.0f/(1.0f+expf(-lg.w)))*mk.w;  t.w = tg.w*mk.w;
    *(float4*)(pred + i) = p;
    *(float4*)(tgt + i)  = t;
}

template <bool FINAL>
__global__ __launch_bounds__(128) void skel_iter_kernel(const float* __restrict__ xin,
                                                        float* __restrict__ xout,
                                                        const float* __restrict__ other,
                                                        double* __restrict__ acc) {
    alignas(16) __shared__ float sx[4][XH * XS];   // 25.3 KB
    alignas(16) __shared__ float smp[2][MH * XS];  // 12.0 KB

    // XCD-chunked swizzle (kept from R6: dropped FETCH 77->38 MB)
    int hwb = blockIdx.x;
    int bx  = (hwb & 7) * 128 + (hwb >> 3);

    int w0  = (bx & 7) * TW;
    int h0  = ((bx >> 3) & 7) * TW;
    int gd0 = ((bx >> 6) & 7) * CD;
    int b   = bx >> 9;
    int tid = threadIdx.x;
    int r   = tid >> 2;        // 0..31 : output row within tile
    int k   = tid & 3;         // 0..3  : 8-float col job (floats 8k..8k+7 of output)

    const float* xb  = xin + b * (D * HW);
    float*       ob  = xout ? (xout + b * (D * HW)) : nullptr;
    const float* otb = other + b * (D * HW);

    const float4 inf4  = make_float4( INFINITY,  INFINITY,  INFINITY,  INFINITY);
    const float4 ninf4 = make_float4(-INFINITY, -INFINITY, -INFINITY, -INFINITY);

    // staging maps over the 36x10 group plane:
    //  A: (r, k)   B: (r, k+4)   C: (r, k+8) if k<2   D: rows 32..35 via 16 thr/row
    int  d_r = 32 + (tid >> 4);
    int  d_g = tid & 15;
    bool has_c = (k < 2);
    bool has_d = (tid < 64) && (d_g < 10);

    auto fetch = [&](const float* src, int xr, int g) -> float4 {
        int gh = h0 - 2 + xr;
        int gw = w0 - 4 + 4 * g;   // multiple of 4: group fully in or out
        if ((unsigned)gh < (unsigned)H && (unsigned)gw <= 252u)
            return *(const float4*)(src + gh * W + gw);
        return inf4;
    };

    float4 La, Lb, Lc, Ld;     // pending plane (issued previous iter)
    auto issue_loads = [&](int p) {
        if (p < 0 || p >= D) { La = Lb = Lc = Ld = inf4; return; }
        const float* src = xb + p * HW;
        La = fetch(src, r, k);
        Lb = fetch(src, r, k + 4);
        Lc = has_c ? fetch(src, r, k + 8) : inf4;
        Ld = has_d ? fetch(src, d_r, d_g) : inf4;
    };
    auto store_vals = [&](int p, float4 va, float4 vb, float4 vc, float4 vd) {
        float* dst = sx[p & 3];
        *(float4*)&dst[r * XS + 4 * k]       = va;
        *(float4*)&dst[r * XS + 4 * (k + 4)] = vb;
        if (has_c) *(float4*)&dst[r * XS + 4 * (k + 8)] = vc;
        if (has_d) *(float4*)&dst[d_r * XS + 4 * d_g]   = vd;
    };

    // 7-point cross min for mp floats 8mk..8mk+7 of mp row mr (12 b128 reads)
    auto cross8 = [&](const float* xm, const float* xc, const float* xp,
                      int mr, int mk, float4& lo, float4& hi) {
        int xo = (mr + 1) * XS + 8 * mk;       // center x row, float 8mk
        float4 Gm1 = (mk > 0) ? *(const float4*)&xc[xo - 4] : inf4;
        float4 G0  = *(const float4*)&xc[xo];
        float4 G1  = *(const float4*)&xc[xo + 4];
        float4 G2  = (mk < 4) ? *(const float4*)&xc[xo + 8] : inf4;
        lo = vmin4(vmin4(sh3(Gm1, G0), G0), sh1(G0, G1));
        hi = vmin4(vmin4(sh3(G0, G1), G1), sh1(G1, G2));
        int xu = mr * XS + 8 * mk;
        int xd = (mr + 2) * XS + 8 * mk;
        lo = vmin4(lo, *(const float4*)&xc[xu]);
        hi = vmin4(hi, *(const float4*)&xc[xu + 4]);
        lo = vmin4(lo, *(const float4*)&xc[xd]);
        hi = vmin4(hi, *(const float4*)&xc[xd + 4]);
        lo = vmin4(lo, *(const float4*)&xm[xo]);
        hi = vmin4(hi, *(const float4*)&xm[xo + 4]);
        lo = vmin4(lo, *(const float4*)&xp[xo]);
        hi = vmin4(hi, *(const float4*)&xp[xo + 4]);
        int gh = h0 - 1 + mr;
        if ((unsigned)gh >= (unsigned)H) { lo = ninf4; hi = ninf4; return; }
        int gwb = w0 - 4 + 8 * mk;    // OOB columns -> -INF (max stage ignores)
        lo.x = ((unsigned)(gwb + 0) < (unsigned)W) ? lo.x : -INFINITY;
        lo.y = ((unsigned)(gwb + 1) < (unsigned)W) ? lo.y : -INFINITY;
        lo.z = ((unsigned)(gwb + 2) < (unsigned)W) ? lo.z : -INFINITY;
        lo.w = ((unsigned)(gwb + 3) < (unsigned)W) ? lo.w : -INFINITY;
        hi.x = ((unsigned)(gwb + 4) < (unsigned)W) ? hi.x : -INFINITY;
        hi.y = ((unsigned)(gwb + 5) < (unsigned)W) ? hi.y : -INFINITY;
        hi.z = ((unsigned)(gwb + 6) < (unsigned)W) ? hi.z : -INFINITY;
        hi.w = ((unsigned)(gwb + 7) < (unsigned)W) ? hi.w : -INFINITY;
    };

    // Prologue: planes gd0-2..gd0 resident; pending regs hold plane gd0+1.
    issue_loads(gd0 - 2); store_vals(gd0 - 2, La, Lb, Lc, Ld);
    issue_loads(gd0 - 1); store_vals(gd0 - 1, La, Lb, Lc, Ld);
    issue_loads(gd0);     store_vals(gd0,     La, Lb, Lc, Ld);
    issue_loads(gd0 + 1);
    __syncthreads();

    float4 h2lo = ninf4, h2hi = ninf4;   // hw9 ring: plane q-2
    float4 h1lo = ninf4, h1hi = ninf4;   //           plane q-1
    float4 m1lo = ninf4, m1hi = ninf4;   // mp center of plane q-1
    double s0 = 0.0, s1 = 0.0;

    for (int q = gd0 - 1; q <= gd0 + CD; ++q) {
        // (1) capture pending plane (q+2), issue loads for q+3 (depth-2)
        float4 Ca = La, Cb = Lb, Cc = Lc, Cd = Ld;
        int cp = q + 2;
        if (q + 3 <= gd0 + CD + 1) issue_loads(q + 3);

        // (2) mp[q] -> smp[q&1]; prev reader was hw9[q-2] (post-barrier_{q-2}),
        // barrier_{q-1} separates. 170 8-float jobs: 128 main + 42 packed extras.
        bool qv = (q >= 0 && q < D);
        float* mp = smp[q & 1];
        if (qv) {
            const float* xm = sx[(q - 1) & 3];
            const float* xc = sx[q & 3];
            const float* xp = sx[(q + 1) & 3];
            float4 lo, hi;
            cross8(xm, xc, xp, r, k, lo, hi);
            *(float4*)&mp[r * XS + 8 * k]     = lo;
            *(float4*)&mp[r * XS + 8 * k + 4] = hi;
            if (tid < 42) {
                int mr2, mk2;
                if (tid < 34) { mr2 = tid; mk2 = 4; }
                else          { mr2 = 32 + ((tid - 34) >> 2); mk2 = (tid - 34) & 3; }
                cross8(xm, xc, xp, mr2, mk2, lo, hi);
                *(float4*)&mp[mr2 * XS + 8 * mk2]     = lo;
                *(float4*)&mp[mr2 * XS + 8 * mk2 + 4] = hi;
            }
        }

        // hoist x center for out[d=q-1] (slot (q-1)&3 stable until iter q+3)
        int d = q - 1;
        bool dv = (d >= gd0);
        float4 xvlo = inf4, xvhi = inf4;
        if (dv) {
            const float* xdp = sx[d & 3];
            xvlo = *(const float4*)&xdp[(r + 2) * XS + 8 * k + 4];
            xvhi = *(const float4*)&xdp[(r + 2) * XS + 8 * k + 8];
        }

        // (3) commit plane cp=q+2; old content x[q-2] last read pre-barrier_{q-1}
        if (cp <= gd0 + CD + 1) store_vals(cp, Ca, Cb, Cc, Cd);

        __syncthreads();   // the ONLY barrier per plane

        // (4) hw9[q]: 3x3 HW max of mp[q]; centers are mp floats 8k+4..8k+11
        float4 hclo, hchi, mclo, mchi;
        if (qv) {
            const float* m = smp[q & 1];
            int base = r * XS + 8 * k;
            float4 a0, a1, a2, a3, t0lo, t0hi, t1lo, t1hi, t2lo, t2hi;
            a0 = *(const float4*)&m[base];      a1 = *(const float4*)&m[base + 4];
            a2 = *(const float4*)&m[base + 8];  a3 = *(const float4*)&m[base + 12];
            t0lo = vmax4(vmax4(sh3(a0, a1), a1), sh1(a1, a2));
            t0hi = vmax4(vmax4(sh3(a1, a2), a2), sh1(a2, a3));
            base += XS;
            a0 = *(const float4*)&m[base];      a1 = *(const float4*)&m[base + 4];
            a2 = *(const float4*)&m[base + 8];  a3 = *(const float4*)&m[base + 12];
            t1lo = vmax4(vmax4(sh3(a0, a1), a1), sh1(a1, a2));
            t1hi = vmax4(vmax4(sh3(a1, a2), a2), sh1(a2, a3));
            mclo = a1; mchi = a2;
            base += XS;
            a0 = *(const float4*)&m[base];      a1 = *(const float4*)&m[base + 4];
            a2 = *(const float4*)&m[base + 8];  a3 = *(const float4*)&m[base + 12];
            t2lo = vmax4(vmax4(sh3(a0, a1), a1), sh1(a1, a2));
            t2hi = vmax4(vmax4(sh3(a1, a2), a2), sh1(a2, a3));
            hclo = vmax4(t0lo, vmax4(t1lo, t2lo));
            hchi = vmax4(t0hi, vmax4(t1hi, t2hi));
        } else { hclo = hchi = ninf4; mclo = mchi = ninf4; }

        // (5) out[d] = relu(x - (max27 - mp_center))
        if (dv) {
            float4 mxlo = vmax4(h2lo, vmax4(h1lo, hclo));
            float4 mxhi = vmax4(h2hi, vmax4(h1hi, hchi));
            float4 rlo, rhi;
            rlo.x = fmaxf(xvlo.x - (mxlo.x - m1lo.x), 0.0f);
            rlo.y = fmaxf(xvlo.y - (mxlo.y - m1lo.y), 0.0f);
            rlo.z = fmaxf(xvlo.z - (mxlo.z - m1lo.z), 0.0f);
            rlo.w = fmaxf(xvlo.w - (mxlo.w - m1lo.w), 0.0f);
            rhi.x = fmaxf(xvhi.x - (mxhi.x - m1hi.x), 0.0f);
            rhi.y = fmaxf(xvhi.y - (mxhi.y - m1hi.y), 0.0f);
            rhi.z = fmaxf(xvhi.z - (mxhi.z - m1hi.z), 0.0f);
            rhi.w = fmaxf(xvhi.w - (mxhi.w - m1hi.w), 0.0f);
            long off = (long)d * HW + (h0 + r) * W + (w0 + 8 * k);
            if constexpr (FINAL) {
                float4 olo = *(const float4*)(otb + off);
                float4 ohi = *(const float4*)(otb + off + 4);
                s0 += (double)(rlo.x * olo.x) + (double)(rlo.y * olo.y)
                    + (double)(rlo.z * olo.z) + (double)(rlo.w * olo.w)
                    + (double)(rhi.x * ohi.x) + (double)(rhi.y * ohi.y)
                    + (double)(rhi.z * ohi.z) + (double)(rhi.w * ohi.w);
                s1 += (double)rlo.x + (double)rlo.y + (double)rlo.z + (double)rlo.w
                    + (double)rhi.x + (double)rhi.y + (double)rhi.z + (double)rhi.w;
            } else {
                *(float4*)(ob + off)     = rlo;
                *(float4*)(ob + off + 4) = rhi;
            }
        }
        h2lo = h1lo; h1lo = hclo;  h2hi = h1hi; h1hi = hchi;
        m1lo = mclo; m1hi = mchi;
    }

    if constexpr (FINAL) {
        for (int off = 32; off > 0; off >>= 1) {
            s0 += __shfl_down(s0, off, 64);
            s1 += __shfl_down(s1, off, 64);
        }
        if ((tid & 63) == 0) {
            atomicAdd(&acc[0], s0);
            atomicAdd(&acc[1], s1);
        }
    }
}

__global__ void final_kernel(const double* __restrict__ acc, float* __restrict__ out) {
    double clrecall = (acc[0] + 1e-12) / (acc[1] + 1e-12);
    double clacc    = (acc[2] + 1e-12) / (acc[3] + 1e-12);
    double cldice   = 2.0 * clrecall * clacc / (clrecall + clacc + 1e-12);
    out[0] = (float)(1.0 - cldice);
}

extern "C" void kernel_launch(void* const* d_in, const int* in_sizes, int n_in,
                              void* d_out, int out_size, void* d_ws, size_t ws_size,
                              hipStream_t stream) {
    const float* logits = (const float*)d_in[0];
    const float* target = (const float*)d_in[1];
    const float* mask   = (const float*)d_in[2];
    float* out = (float*)d_out;

    // Workspace layout (floats): pred | tgt | xA | xB | acc(4 doubles)
    float* pred = (float*)d_ws;
    float* tgt  = pred + NV;
    float* xA   = tgt + NV;
    float* xB   = xA + NV;
    double* acc = (double*)(xB + NV);

    hipMemsetAsync(acc, 0, 4 * sizeof(double), stream);

    prep_kernel<<<dim3(NV / 1024), dim3(256), 0, stream>>>(logits, target, mask, pred, tgt);

    dim3 blk(128);
    dim3 sgrd(1024);  // 2 batches x 8 D-chunks x 8x8 tiles = 4 blocks/CU

    // skeletonize(tgt): tgt -> A -> B -> A -> B -> (fused reduce vs pred)
    for (int it = 0; it < 4; ++it) {
        const float* in = (it == 0) ? tgt : ((it & 1) ? xA : xB);
        float* outb = (it & 1) ? xB : xA;
        skel_iter_kernel<false><<<sgrd, blk, 0, stream>>>(in, outb, pred, acc);
    }
    skel_iter_kernel<true><<<sgrd, blk, 0, stream>>>(xB, nullptr, pred, acc);

    // skeletonize(pred): pred -> A -> B -> A -> B -> (fused reduce vs tgt)
    for (int it = 0; it < 4; ++it) {
        const float* in = (it == 0) ? pred : ((it & 1) ? xA : xB);
        float* outb = (it & 1) ? xB : xA;
        skel_iter_kernel<false><<<sgrd, blk, 0, stream>>>(in, outb, tgt, acc);
    }
    skel_iter_kernel<true><<<sgrd, blk, 0, stream>>>(xB, nullptr, tgt, acc + 2);

    final_kernel<<<1, 1, 0, stream>>>(acc, out);
}